// Round 7
// baseline (37.024 us; speedup 1.0000x reference)
//
#include <hip/hip_runtime.h>
#include <hip/hip_bf16.h>

#define BB 4
#define NN 512
#define CC 32
#define KK 4      // K+1
#define HH 4
#define AOUT 256

// ws float-index offsets (si/sj)
#define WS_SI_F   0
#define WS_SII_F  (BB*NN*HH)
#define WS_SJR_F  (2*BB*NN*HH)
#define WS_SJI_F  (3*BB*NN*HH)
// ws byte offsets
#define XT_BASE   131072         // bf16 X tiles [part][b][jb16] x 2048 B
#define LX_BASE   393216         // bf16 LX [bn] x 2048 B   (4 MB)
#define BRE_BASE  4587520        // bf16 B_re fragments, 128 KB
#define BIM_BASE  4718592        // bf16 B_im fragments, 128 KB

typedef __attribute__((ext_vector_type(8))) short bf16x8;
typedef __attribute__((ext_vector_type(4))) float f32x4;

__device__ __forceinline__ ushort f2bfu(float f){
    union { __hip_bfloat16 h; ushort u; } cv;
    cv.h = __float2bfloat16(f);
    return cv.u;
}
__device__ __forceinline__ short f2bfs(float f){ return (short)f2bfu(f); }
__device__ __forceinline__ float bfu2f(unsigned int u){ return __uint_as_float(u << 16); }

// ---------------------------------------------------------------------------
// Fused prep kernel: grid 96 x 256  (unchanged from round 6)
// ---------------------------------------------------------------------------
__global__ __launch_bounds__(256) void prep_kernel(
    const float* __restrict__ Xr, const float* __restrict__ Xi,
    const float* __restrict__ AWr, const float* __restrict__ AWi,
    const float* __restrict__ Wr, const float* __restrict__ Wi,
    float* __restrict__ ws, char* __restrict__ wsB)
{
    const int blk = blockIdx.x;
    const int t = threadIdx.x;

    if (blk < 32) {
        const int row = blk*64 + (t >> 2);
        const int q = t & 3;
        const float* xr = Xr + (size_t)row*CC + q*8;
        const float* xi = Xi + (size_t)row*CC + q*8;
        float4 xr4[2], xi4[2];
        xr4[0] = *(const float4*)xr;  xr4[1] = *(const float4*)(xr + 4);
        xi4[0] = *(const float4*)xi;  xi4[1] = *(const float4*)(xi + 4);

        float sir[HH] = {0,0,0,0}, sii[HH] = {0,0,0,0};
        float sjr[HH] = {0,0,0,0}, sji[HH] = {0,0,0,0};
        #pragma unroll
        for (int e = 0; e < 8; ++e) {
            float xrc = ((const float*)&xr4[e>>2])[e & 3];
            float xic = ((const float*)&xi4[e>>2])[e & 3];
            int c = q*8 + e;
            float4 w1r = *(const float4*)(AWr + c*HH);
            float4 w1i = *(const float4*)(AWi + c*HH);
            float4 w2r = *(const float4*)(AWr + (CC + c)*HH);
            float4 w2i = *(const float4*)(AWi + (CC + c)*HH);
            #pragma unroll
            for (int h = 0; h < HH; ++h) {
                float r1 = ((const float*)&w1r)[h], i1 = ((const float*)&w1i)[h];
                float r2 = ((const float*)&w2r)[h], i2 = ((const float*)&w2i)[h];
                sir[h] = fmaf(xrc, r1, fmaf(-xic, i1, sir[h]));
                sii[h] = fmaf(xrc, i1, fmaf( xic, r1, sii[h]));
                sjr[h] = fmaf(xrc, r2, fmaf(-xic, i2, sjr[h]));
                sji[h] = fmaf(xrc, i2, fmaf( xic, r2, sji[h]));
            }
        }
        float A[HH], Bv[HH];
        #pragma unroll
        for (int h = 0; h < HH; ++h) {
            float sendA = (q & 1) ? sir[h] : sii[h];
            float keepA = (q & 1) ? sii[h] : sir[h];
            A[h] = keepA + __shfl_xor(sendA, 1);
            float sendB = (q & 1) ? sjr[h] : sji[h];
            float keepB = (q & 1) ? sji[h] : sjr[h];
            Bv[h] = keepB + __shfl_xor(sendB, 1);
        }
        float tot[HH];
        #pragma unroll
        for (int h = 0; h < HH; ++h) {
            float send = (q & 2) ? A[h] : Bv[h];
            float keep = (q & 2) ? Bv[h] : A[h];
            tot[h] = keep + __shfl_xor(send, 2);
        }
        float4 v = make_float4(tot[0], tot[1], tot[2], tot[3]);
        *(float4*)(ws + (size_t)q*(BB*NN*HH) + (size_t)row*HH) = v;
    } else if (blk < 64) {
        int bid = (blk - 32)*4 + (t >> 6);   // 0..127: part*64 + b*16 + jb
        int part = bid >> 6, b = (bid >> 4) & 3, jb = bid & 15;
        const float* X = part ? Xi : Xr;
        int lane = t & 63;
        int c = lane & 31, jh = lane >> 5;

        unsigned int w[8];
        #pragma unroll
        for (int qq = 0; qq < 8; ++qq) {
            int ji = jh*16 + qq*2;
            float f0 = X[((size_t)b*NN + jb*32 + ji  )*CC + c];
            float f1 = X[((size_t)b*NN + jb*32 + ji+1)*CC + c];
            w[qq] = (unsigned int)f2bfu(f0) | ((unsigned int)f2bfu(f1) << 16);
        }
        char* tile = wsB + XT_BASE + (((size_t)(part*4 + b)*16 + jb) * 2048);
        uint4* dst = (uint4*)(tile + c*64 + jh*32);
        dst[0] = make_uint4(w[0], w[1], w[2], w[3]);
        dst[1] = make_uint4(w[4], w[5], w[6], w[7]);
    } else {
        int idx = (blk - 64)*256 + t;        // 0..8191
        int l  = idx & 63;
        int s  = (idx >> 6) & 7;
        int Nt = (idx >> 9) & 3;
        int h  = idx >> 11;
        int p = Nt*16 + (l & 15), o = p*4 + h;
        int e8 = (l >> 4) * 8;
        unsigned int re_w[4], im_w[4];
        #pragma unroll
        for (int qq = 0; qq < 4; ++qq) {
            unsigned int rw = 0, iw = 0;
            #pragma unroll
            for (int half = 0; half < 2; ++half) {
                int kpos = s*32 + e8 + qq*2 + half;
                int ri = kpos >> 7, kk = (kpos >> 5) & 3, c = kpos & 31;
                float wr = Wr[(size_t)(kk*CC + c)*AOUT + o];
                float wi = Wi[(size_t)(kk*CC + c)*AOUT + o];
                unsigned int vre = f2bfu(ri ? -wi : wr);
                unsigned int vim = f2bfu(ri ?  wr : wi);
                rw |= vre << (16*half);
                iw |= vim << (16*half);
            }
            re_w[qq] = rw; im_w[qq] = iw;
        }
        size_t fo = ((size_t)((h*4 + Nt)*8 + s))*1024 + (size_t)l*16;
        *(uint4*)(wsB + BRE_BASE + fo) = make_uint4(re_w[0], re_w[1], re_w[2], re_w[3]);
        *(uint4*)(wsB + BIM_BASE + fo) = make_uint4(im_w[0], im_w[1], im_w[2], im_w[3]);
    }
}

// ---------------------------------------------------------------------------
// Main kernel: one block per (b,n), 256 threads (4 waves). LDS ~19 KB.
//  P1: t<128 load Lr rows 0-3 (j=4(t&127)) + compute mask -> amb; t>=128 Li
//  P2: scores pre-barrier in regs; mask applied post-S1; 3 barrier reductions
//  P3: wave w owns j in [w*128, w*128+128): 4 MFMA steps, 2-deep B pipe
//  epilogue: 2-stage cross-wave tree (w1->w0, w3->w2; then ct-split swap)
// ---------------------------------------------------------------------------
__global__ __launch_bounds__(256) void cheb_main_kernel(
    const float* __restrict__ Lr_g, const float* __restrict__ Li_g,
    const float* __restrict__ abr, const float* __restrict__ abi,
    const float* __restrict__ par, const float* __restrict__ pai,
    const float* __restrict__ ws, char* __restrict__ wsB)
{
    __shared__ ushort Lf[8][528];      // bf16 bits; 8448 B (rows 0-3 Lr, 4-7 Li)
    __shared__ float awf[HH][520];     // 8320 B; reused as pbufA (2048 floats)
    __shared__ float amb[512];         // 2048 B mask sums
    __shared__ float wredm[4][HH];
    __shared__ float wreds[4][HH];

    const int bn = blockIdx.x;
    const int b = bn >> 9;
    const int n = bn & (NN - 1);
    const int t = threadIdx.x;
    const int l = t & 63;
    const int w = t >> 6;
    const int jw2 = 2*t;               // P2 j-window {jw2, jw2+1}

    // ---- hoisted loads: si, sj ----
    const float4 si_r4 = *(const float4*)(ws + WS_SI_F  + bn*HH);
    const float4 si_i4 = *(const float4*)(ws + WS_SII_F + bn*HH);
    float4 sjr[2], sji[2];
    #pragma unroll
    for (int e = 0; e < 2; ++e) {
        sjr[e] = *(const float4*)(ws + WS_SJR_F + ((size_t)b*NN + jw2 + e)*HH);
        sji[e] = *(const float4*)(ws + WS_SJI_F + ((size_t)b*NN + jw2 + e)*HH);
    }
    const float a_r = par[0], a_i = pai[0];

    // ---- B-fragment prefetch (P3 steps 0,1 of this wave) ----
    const char* xtR = wsB + XT_BASE + ((size_t)(0*4 + b)*16 + w*4)*2048;
    const char* xtI = wsB + XT_BASE + ((size_t)(4   + b)*16 + w*4)*2048;
    const int jg  = l >> 4;
    const int bofs = (l & 15)*64 + jg*16;

#define LB(s, BR0,BR1,BI0,BI1) do {                                           \
        BR0 = *(const bf16x8*)(xtR + (s)*2048 +        bofs);                 \
        BR1 = *(const bf16x8*)(xtR + (s)*2048 + 1024 + bofs);                 \
        BI0 = *(const bf16x8*)(xtI + (s)*2048 +        bofs);                 \
        BI1 = *(const bf16x8*)(xtI + (s)*2048 + 1024 + bofs);                 \
    } while (0)

    bf16x8 pR0,pR1,pI0,pI1, qR0,qR1,qI0,qI1;
    LB(0, pR0,pR1,pI0,pI1);
    LB(1, qR0,qR1,qI0,qI1);

    // ---- P1: stage L as bf16; halves: w0,w1 -> Lr + mask; w2,w3 -> Li ----
    {
        const int half = t >> 7;
        const int jc = (t & 127) * 4;
        const float* src = half ? Li_g : Lr_g;
        float am4[4] = {0.f,0.f,0.f,0.f};
        #pragma unroll
        for (int it = 0; it < 4; ++it) {
            size_t goff = (((size_t)b*KK + it)*NN + n)*NN + jc;
            float4 v = *(const float4*)(src + goff);
            if (half == 0) {
                am4[0] += fabsf(v.x); am4[1] += fabsf(v.y);
                am4[2] += fabsf(v.z); am4[3] += fabsf(v.w);
            }
            ushort4 u;
            u.x = f2bfu(v.x); u.y = f2bfu(v.y); u.z = f2bfu(v.z); u.w = f2bfu(v.w);
            *(ushort4*)&Lf[half*4 + it][jc] = u;
        }
        if (half == 0) *(float4*)&amb[jc] = *(float4*)am4;
    }

    // ---- P2a: scores in registers (pre-barrier) ----
    float sir[HH], sii[HH];
    #pragma unroll
    for (int h = 0; h < HH; ++h) {
        sir[h] = ((const float*)&si_r4)[h] + abr[h];
        sii[h] = ((const float*)&si_i4)[h] + abi[h];
    }
    float v[2][HH];
    #pragma unroll
    for (int e = 0; e < 2; ++e) {
        const float* sjrp = (const float*)&sjr[e];
        const float* sjip = (const float*)&sji[e];
        #pragma unroll
        for (int h = 0; h < HH; ++h) {
            float sr = sir[h] + sjrp[h];
            sr = sr >= 0.f ? sr : a_r * sr;
            float sv = sii[h] + sjip[h];
            sv = sv >= 0.f ? sv : a_i * sv;
            v[e][h] = sr*sr + sv*sv;
        }
    }
    __syncthreads();                   // S1: Lf + amb visible

    // ---- P2b: mask + max reduce ----
    {
        const float NEG = -1e9f;
        const float MASKED = NEG*NEG + NEG*NEG;
        float a0 = amb[jw2], a1 = amb[jw2 + 1];
        bool m0 = a0 > 1e-9f, m1 = a1 > 1e-9f;
        #pragma unroll
        for (int h = 0; h < HH; ++h) {
            v[0][h] = m0 ? v[0][h] : MASKED;
            v[1][h] = m1 ? v[1][h] : MASKED;
        }
    }
    float pmax[HH];
    #pragma unroll
    for (int h = 0; h < HH; ++h) {
        pmax[h] = fmaxf(v[0][h], v[1][h]);
        #pragma unroll
        for (int off = 32; off > 0; off >>= 1)
            pmax[h] = fmaxf(pmax[h], __shfl_xor(pmax[h], off));
    }
    if (l == 0) { wredm[w][0]=pmax[0]; wredm[w][1]=pmax[1]; wredm[w][2]=pmax[2]; wredm[w][3]=pmax[3]; }
    __syncthreads();                   // S2: wredm visible

    float hm[HH];
    #pragma unroll
    for (int h = 0; h < HH; ++h)
        hm[h] = fmaxf(fmaxf(wredm[0][h], wredm[1][h]), fmaxf(wredm[2][h], wredm[3][h]));

    float psum[HH];
    #pragma unroll
    for (int h = 0; h < HH; ++h) {
        float e0 = __expf(v[0][h] - hm[h]);
        float e1 = __expf(v[1][h] - hm[h]);
        float2 ev = make_float2(e0, e1);
        *(float2*)&awf[h][jw2] = ev;
        psum[h] = e0 + e1;
        #pragma unroll
        for (int off = 32; off > 0; off >>= 1)
            psum[h] += __shfl_xor(psum[h], off);
    }
    if (l == 0) { wreds[w][0]=psum[0]; wreds[w][1]=psum[1]; wreds[w][2]=psum[2]; wreds[w][3]=psum[3]; }
    __syncthreads();                   // S3: awf + wreds visible

    float inv[HH];
    #pragma unroll
    for (int h = 0; h < HH; ++h)
        inv[h] = 1.0f / (((wreds[0][h] + wreds[1][h]) + (wreds[2][h] + wreds[3][h])));

    // ---- P3: MFMA; wave w owns j in [w*128, w*128+128), 4 steps ----
    const int r_a = l & 15;            // A row = k*4+h
    const int k_a = r_a >> 2, h_a = r_a & 3;

    f32x4 acc[8];                      // RR0 RR1 II0 II1 RI0 RI1 IR0 IR1
    #pragma unroll
    for (int a = 0; a < 8; ++a) acc[a] = (f32x4){0.f,0.f,0.f,0.f};

#define COMP(s, BR0,BR1,BI0,BI1) do {                                         \
        const int j0_ = w*128 + (s)*32 + jg*8;                                \
        bf16x8 LR8 = *(const bf16x8*)&Lf[k_a][j0_];                           \
        bf16x8 LI8 = *(const bf16x8*)&Lf[4 + k_a][j0_];                       \
        float aww_[8];                                                        \
        *(float4*)&aww_[0] = *(const float4*)&awf[h_a][j0_];                  \
        *(float4*)&aww_[4] = *(const float4*)&awf[h_a][j0_ + 4];              \
        bf16x8 Ar_, Ai_;                                                      \
        _Pragma("unroll")                                                     \
        for (int e_ = 0; e_ < 8; ++e_) {                                      \
            Ar_[e_] = f2bfs(bfu2f((ushort)LR8[e_]) * aww_[e_]);               \
            Ai_[e_] = f2bfs(bfu2f((ushort)LI8[e_]) * aww_[e_]);               \
        }                                                                     \
        acc[0] = __builtin_amdgcn_mfma_f32_16x16x32_bf16(Ar_, BR0, acc[0],0,0,0); \
        acc[1] = __builtin_amdgcn_mfma_f32_16x16x32_bf16(Ar_, BR1, acc[1],0,0,0); \
        acc[2] = __builtin_amdgcn_mfma_f32_16x16x32_bf16(Ai_, BI0, acc[2],0,0,0); \
        acc[3] = __builtin_amdgcn_mfma_f32_16x16x32_bf16(Ai_, BI1, acc[3],0,0,0); \
        acc[4] = __builtin_amdgcn_mfma_f32_16x16x32_bf16(Ar_, BI0, acc[4],0,0,0); \
        acc[5] = __builtin_amdgcn_mfma_f32_16x16x32_bf16(Ar_, BI1, acc[5],0,0,0); \
        acc[6] = __builtin_amdgcn_mfma_f32_16x16x32_bf16(Ai_, BR0, acc[6],0,0,0); \
        acc[7] = __builtin_amdgcn_mfma_f32_16x16x32_bf16(Ai_, BR1, acc[7],0,0,0); \
    } while (0)

    COMP(0, pR0,pR1,pI0,pI1);
    LB(2, pR0,pR1,pI0,pI1);
    COMP(1, qR0,qR1,qI0,qI1);
    LB(3, qR0,qR1,qI0,qI1);
    COMP(2, pR0,pR1,pI0,pI1);
    COMP(3, qR0,qR1,qI0,qI1);
#undef LB
#undef COMP

    __syncthreads();                   // S4: all awf/Lf reads done

    // ---- epilogue: 2-stage cross-wave tree ----
    float* pbufA = &awf[0][0];         // 2048 floats
    float* pbufB = (float*)&Lf[0][0];  // 2112 floats available
    if (w == 1) {
        #pragma unroll
        for (int a = 0; a < 8; ++a)
            #pragma unroll
            for (int r = 0; r < 4; ++r)
                pbufA[(a*4 + r)*64 + l] = acc[a][r];
    } else if (w == 3) {
        #pragma unroll
        for (int a = 0; a < 8; ++a)
            #pragma unroll
            for (int r = 0; r < 4; ++r)
                pbufB[(a*4 + r)*64 + l] = acc[a][r];
    }
    __syncthreads();                   // S5
    if (w == 0) {
        #pragma unroll
        for (int a = 0; a < 8; ++a)
            #pragma unroll
            for (int r = 0; r < 4; ++r)
                acc[a][r] += pbufA[(a*4 + r)*64 + l];
        // hand odd (ct=1) accs to w2
        #pragma unroll
        for (int ao = 0; ao < 4; ++ao)
            #pragma unroll
            for (int r = 0; r < 4; ++r)
                pbufB[1024 + (ao*4 + r)*64 + l] = acc[2*ao + 1][r];
    } else if (w == 2) {
        #pragma unroll
        for (int a = 0; a < 8; ++a)
            #pragma unroll
            for (int r = 0; r < 4; ++r)
                acc[a][r] += pbufB[(a*4 + r)*64 + l];
        // hand even (ct=0) accs to w0
        #pragma unroll
        for (int ae = 0; ae < 4; ++ae)
            #pragma unroll
            for (int r = 0; r < 4; ++r)
                pbufA[(ae*4 + r)*64 + l] = acc[2*ae][r];
    }
    __syncthreads();                   // S6

    const int kk = l >> 4, lc = l & 15;
    char* lxp = wsB + LX_BASE + (size_t)bn*2048;
    if (w == 0) {
        #pragma unroll
        for (int ae = 0; ae < 4; ++ae)
            #pragma unroll
            for (int r = 0; r < 4; ++r)
                acc[2*ae][r] += pbufA[(ae*4 + r)*64 + l];
        #pragma unroll
        for (int r = 0; r < 4; ++r) {   // r == h
            float iv = inv[r];
            float vr = (acc[0][r] - acc[2][r]) * iv;
            float vi = (acc[4][r] + acc[6][r]) * iv;
            *(ushort*)(lxp + r*512 +       kk*64 + lc*2) = f2bfu(vr);
            *(ushort*)(lxp + r*512 + 256 + kk*64 + lc*2) = f2bfu(vi);
        }
    } else if (w == 2) {
        #pragma unroll
        for (int ao = 0; ao < 4; ++ao)
            #pragma unroll
            for (int r = 0; r < 4; ++r)
                acc[2*ao + 1][r] += pbufB[1024 + (ao*4 + r)*64 + l];
        const int c = 16 + lc;
        #pragma unroll
        for (int r = 0; r < 4; ++r) {
            float iv = inv[r];
            float vr = (acc[1][r] - acc[3][r]) * iv;
            float vi = (acc[5][r] + acc[7][r]) * iv;
            *(ushort*)(lxp + r*512 +       kk*64 + c*2) = f2bfu(vr);
            *(ushort*)(lxp + r*512 + 256 + kk*64 + c*2) = f2bfu(vi);
        }
    }
}

// ---------------------------------------------------------------------------
// Out GEMM: Y[bn,o] = [LXr|LXi] @ Bre/Bim (K=256), + bias.
// grid 512 blocks (Mtile*4 + Nt) x 256 thr; wave = h.
// ---------------------------------------------------------------------------
__global__ __launch_bounds__(256) void out_gemm_kernel(
    const char* __restrict__ wsB,
    const float* __restrict__ bsr, const float* __restrict__ bsi,
    float* __restrict__ out)
{
    const int Mtile = blockIdx.x >> 2;
    const int Nt    = blockIdx.x & 3;
    const int t = threadIdx.x, l = t & 63, h = t >> 6;

    const char* abase = wsB + LX_BASE + ((size_t)(Mtile*16 + (l & 15)))*2048
                        + h*512 + (l >> 4)*16;
    f32x4 are = (f32x4){0.f,0.f,0.f,0.f};
    f32x4 aim = (f32x4){0.f,0.f,0.f,0.f};
    const size_t fbase = ((size_t)((h*4 + Nt)*8))*1024 + (size_t)l*16;
    const char* bre = wsB + BRE_BASE + fbase;
    const char* bim = wsB + BIM_BASE + fbase;
    #pragma unroll
    for (int s = 0; s < 8; ++s) {
        bf16x8 Af = *(const bf16x8*)(abase + s*64);
        bf16x8 Br = *(const bf16x8*)(bre + s*1024);
        bf16x8 Bi = *(const bf16x8*)(bim + s*1024);
        are = __builtin_amdgcn_mfma_f32_16x16x32_bf16(Af, Br, are, 0, 0, 0);
        aim = __builtin_amdgcn_mfma_f32_16x16x32_bf16(Af, Bi, aim, 0, 0, 0);
    }
    const int p = Nt*16 + (l & 15), o = p*4 + h;
    const float vbr = bsr[o], vbi = bsi[o];
    #pragma unroll
    for (int r = 0; r < 4; ++r) {
        int bn = Mtile*16 + (l >> 4)*4 + r;
        out[(size_t)bn*AOUT + o] = are[r] + vbr;
        out[(size_t)BB*NN*AOUT + (size_t)bn*AOUT + o] = aim[r] + vbi;
    }
}

// ---------------------------------------------------------------------------
extern "C" void kernel_launch(void* const* d_in, const int* in_sizes, int n_in,
                              void* d_out, int out_size, void* d_ws, size_t ws_size,
                              hipStream_t stream)
{
    const float* Xr  = (const float*)d_in[0];
    const float* Xi  = (const float*)d_in[1];
    const float* Lr  = (const float*)d_in[2];
    const float* Li  = (const float*)d_in[3];
    const float* Wr  = (const float*)d_in[4];
    const float* Wi  = (const float*)d_in[5];
    const float* AWr = (const float*)d_in[6];
    const float* AWi = (const float*)d_in[7];
    const float* abr = (const float*)d_in[8];
    const float* abi = (const float*)d_in[9];
    const float* par = (const float*)d_in[10];
    const float* pai = (const float*)d_in[11];
    const float* bsr = (const float*)d_in[12];
    const float* bsi = (const float*)d_in[13];
    float* ws  = (float*)d_ws;
    char*  wsB = (char*)d_ws;
    float* out = (float*)d_out;

    hipLaunchKernelGGL(prep_kernel, dim3(96), dim3(256), 0, stream,
                       Xr, Xi, AWr, AWi, Wr, Wi, ws, wsB);
    hipLaunchKernelGGL(cheb_main_kernel, dim3(BB*NN), dim3(256), 0, stream,
                       Lr, Li, abr, abi, par, pai, ws, wsB);
    hipLaunchKernelGGL(out_gemm_kernel, dim3(512), dim3(256), 0, stream,
                       wsB, bsr, bsi, out);
}

// Round 8
// 33.644 us; speedup vs baseline: 1.1004x; 1.1004x over previous
//
#include <hip/hip_runtime.h>
#include <hip/hip_bf16.h>

#define BB 4
#define NN 512
#define CC 32
#define KK 4      // K+1
#define HH 4
#define AOUT 256

// ws float-index offsets (si/sj)
#define WS_SI_F   0
#define WS_SII_F  (BB*NN*HH)
#define WS_SJR_F  (2*BB*NN*HH)
#define WS_SJI_F  (3*BB*NN*HH)
// ws byte offsets
#define XT_BASE   131072         // bf16 X tiles [part][b][jb16] x 2048 B
#define LX_BASE   393216         // bf16 LX [bn] x 2048 B   (4 MB)
#define BRE_BASE  4587520        // bf16 B_re fragments, 128 KB
#define BIM_BASE  4718592        // bf16 B_im fragments, 128 KB

typedef __attribute__((ext_vector_type(8))) short bf16x8;
typedef __attribute__((ext_vector_type(4))) float f32x4;

__device__ __forceinline__ ushort f2bfu(float f){
    union { __hip_bfloat16 h; ushort u; } cv;
    cv.h = __float2bfloat16(f);
    return cv.u;
}
__device__ __forceinline__ short f2bfs(float f){ return (short)f2bfu(f); }
__device__ __forceinline__ float bfu2f(unsigned int u){ return __uint_as_float(u << 16); }

// ---------------------------------------------------------------------------
// Fused prep kernel: grid 96 x 256  (unchanged)
// ---------------------------------------------------------------------------
__global__ __launch_bounds__(256) void prep_kernel(
    const float* __restrict__ Xr, const float* __restrict__ Xi,
    const float* __restrict__ AWr, const float* __restrict__ AWi,
    const float* __restrict__ Wr, const float* __restrict__ Wi,
    float* __restrict__ ws, char* __restrict__ wsB)
{
    const int blk = blockIdx.x;
    const int t = threadIdx.x;

    if (blk < 32) {
        const int row = blk*64 + (t >> 2);
        const int q = t & 3;
        const float* xr = Xr + (size_t)row*CC + q*8;
        const float* xi = Xi + (size_t)row*CC + q*8;
        float4 xr4[2], xi4[2];
        xr4[0] = *(const float4*)xr;  xr4[1] = *(const float4*)(xr + 4);
        xi4[0] = *(const float4*)xi;  xi4[1] = *(const float4*)(xi + 4);

        float sir[HH] = {0,0,0,0}, sii[HH] = {0,0,0,0};
        float sjr[HH] = {0,0,0,0}, sji[HH] = {0,0,0,0};
        #pragma unroll
        for (int e = 0; e < 8; ++e) {
            float xrc = ((const float*)&xr4[e>>2])[e & 3];
            float xic = ((const float*)&xi4[e>>2])[e & 3];
            int c = q*8 + e;
            float4 w1r = *(const float4*)(AWr + c*HH);
            float4 w1i = *(const float4*)(AWi + c*HH);
            float4 w2r = *(const float4*)(AWr + (CC + c)*HH);
            float4 w2i = *(const float4*)(AWi + (CC + c)*HH);
            #pragma unroll
            for (int h = 0; h < HH; ++h) {
                float r1 = ((const float*)&w1r)[h], i1 = ((const float*)&w1i)[h];
                float r2 = ((const float*)&w2r)[h], i2 = ((const float*)&w2i)[h];
                sir[h] = fmaf(xrc, r1, fmaf(-xic, i1, sir[h]));
                sii[h] = fmaf(xrc, i1, fmaf( xic, r1, sii[h]));
                sjr[h] = fmaf(xrc, r2, fmaf(-xic, i2, sjr[h]));
                sji[h] = fmaf(xrc, i2, fmaf( xic, r2, sji[h]));
            }
        }
        float A[HH], Bv[HH];
        #pragma unroll
        for (int h = 0; h < HH; ++h) {
            float sendA = (q & 1) ? sir[h] : sii[h];
            float keepA = (q & 1) ? sii[h] : sir[h];
            A[h] = keepA + __shfl_xor(sendA, 1);
            float sendB = (q & 1) ? sjr[h] : sji[h];
            float keepB = (q & 1) ? sji[h] : sjr[h];
            Bv[h] = keepB + __shfl_xor(sendB, 1);
        }
        float tot[HH];
        #pragma unroll
        for (int h = 0; h < HH; ++h) {
            float send = (q & 2) ? A[h] : Bv[h];
            float keep = (q & 2) ? Bv[h] : A[h];
            tot[h] = keep + __shfl_xor(send, 2);
        }
        float4 v = make_float4(tot[0], tot[1], tot[2], tot[3]);
        *(float4*)(ws + (size_t)q*(BB*NN*HH) + (size_t)row*HH) = v;
    } else if (blk < 64) {
        int bid = (blk - 32)*4 + (t >> 6);   // 0..127: part*64 + b*16 + jb
        int part = bid >> 6, b = (bid >> 4) & 3, jb = bid & 15;
        const float* X = part ? Xi : Xr;
        int lane = t & 63;
        int c = lane & 31, jh = lane >> 5;

        unsigned int w[8];
        #pragma unroll
        for (int qq = 0; qq < 8; ++qq) {
            int ji = jh*16 + qq*2;
            float f0 = X[((size_t)b*NN + jb*32 + ji  )*CC + c];
            float f1 = X[((size_t)b*NN + jb*32 + ji+1)*CC + c];
            w[qq] = (unsigned int)f2bfu(f0) | ((unsigned int)f2bfu(f1) << 16);
        }
        char* tile = wsB + XT_BASE + (((size_t)(part*4 + b)*16 + jb) * 2048);
        uint4* dst = (uint4*)(tile + c*64 + jh*32);
        dst[0] = make_uint4(w[0], w[1], w[2], w[3]);
        dst[1] = make_uint4(w[4], w[5], w[6], w[7]);
    } else {
        int idx = (blk - 64)*256 + t;        // 0..8191
        int l  = idx & 63;
        int s  = (idx >> 6) & 7;
        int Nt = (idx >> 9) & 3;
        int h  = idx >> 11;
        int p = Nt*16 + (l & 15), o = p*4 + h;
        int e8 = (l >> 4) * 8;
        unsigned int re_w[4], im_w[4];
        #pragma unroll
        for (int qq = 0; qq < 4; ++qq) {
            unsigned int rw = 0, iw = 0;
            #pragma unroll
            for (int half = 0; half < 2; ++half) {
                int kpos = s*32 + e8 + qq*2 + half;
                int ri = kpos >> 7, kk = (kpos >> 5) & 3, c = kpos & 31;
                float wr = Wr[(size_t)(kk*CC + c)*AOUT + o];
                float wi = Wi[(size_t)(kk*CC + c)*AOUT + o];
                unsigned int vre = f2bfu(ri ? -wi : wr);
                unsigned int vim = f2bfu(ri ?  wr : wi);
                rw |= vre << (16*half);
                iw |= vim << (16*half);
            }
            re_w[qq] = rw; im_w[qq] = iw;
        }
        size_t fo = ((size_t)((h*4 + Nt)*8 + s))*1024 + (size_t)l*16;
        *(uint4*)(wsB + BRE_BASE + fo) = make_uint4(re_w[0], re_w[1], re_w[2], re_w[3]);
        *(uint4*)(wsB + BIM_BASE + fo) = make_uint4(im_w[0], im_w[1], im_w[2], im_w[3]);
    }
}

// ---------------------------------------------------------------------------
// Main kernel: one block per (b, n-PAIR), 128 threads (2 waves). LDS ~34 KB.
// Rows n0=2m, n1=2m+1 share b => share sj vectors and X B-fragments.
//  top:  load si(both rows), sj(shared), L(both rows, 16 float4)
//  stage row0 + scores row0 ; S1 ; exp row0 + stage row1 + scores row1 ; S2 ;
//  exp row1 ; S3 ; JOINT P3 (B loads shared, 16 MFMA/step) ; S4 ;
//  joint epilogue (2 barriers for both rows)
// ---------------------------------------------------------------------------
__global__ __launch_bounds__(128) void cheb_main_kernel(
    const float* __restrict__ Lr_g, const float* __restrict__ Li_g,
    const float* __restrict__ abr, const float* __restrict__ abi,
    const float* __restrict__ par, const float* __restrict__ pai,
    const float* __restrict__ ws, char* __restrict__ wsB)
{
    __shared__ ushort Lf[2][8][528];     // 16896 B (rows 0-3 Lr, 4-7 Li)
    __shared__ float awf[2][HH][520];    // 16640 B; reused as pbuf per row
    __shared__ float wredm[2][2][HH];
    __shared__ float wreds[2][2][HH];

    const int blk = blockIdx.x;          // b*256 + m
    const int b = blk >> 8;
    const int n0 = (blk & 255) * 2;
    const int bn0 = b*NN + n0;
    const int t = threadIdx.x;
    const int l = t & 63;
    const int w = t >> 6;
    const int jw = 4*t;                  // this thread's j-window

    // ---- hoisted loads ----
    const float4 si_r0 = *(const float4*)(ws + WS_SI_F  + (size_t)bn0*HH);
    const float4 si_i0 = *(const float4*)(ws + WS_SII_F + (size_t)bn0*HH);
    const float4 si_r1 = *(const float4*)(ws + WS_SI_F  + (size_t)(bn0+1)*HH);
    const float4 si_i1 = *(const float4*)(ws + WS_SII_F + (size_t)(bn0+1)*HH);
    float4 sjr[4], sji[4];               // shared between rows
    #pragma unroll
    for (int e = 0; e < 4; ++e) {
        sjr[e] = *(const float4*)(ws + WS_SJR_F + ((size_t)b*NN + jw + e)*HH);
        sji[e] = *(const float4*)(ws + WS_SJI_F + ((size_t)b*NN + jw + e)*HH);
    }
    const float a_r = par[0], a_i = pai[0];

    // L loads for BOTH rows issued up-front (row1 latency hides under row0 work)
    float4 v0[8], v1[8];
    #pragma unroll
    for (int it = 0; it < 8; ++it) {
        const float* src = (it & 4) ? Li_g : Lr_g;
        size_t goff = (((size_t)b*KK + (it & 3))*NN + n0)*NN + jw;
        v0[it] = *(const float4*)(src + goff);
    }
    #pragma unroll
    for (int it = 0; it < 8; ++it) {
        const float* src = (it & 4) ? Li_g : Lr_g;
        size_t goff = (((size_t)b*KK + (it & 3))*NN + (n0+1))*NN + jw;
        v1[it] = *(const float4*)(src + goff);
    }

    // ---- stage row0 + mask ----
    float am0[4] = {0.f,0.f,0.f,0.f};
    #pragma unroll
    for (int it = 0; it < 8; ++it) {
        float4 v = v0[it];
        if (it < 4) {
            am0[0] += fabsf(v.x); am0[1] += fabsf(v.y);
            am0[2] += fabsf(v.z); am0[3] += fabsf(v.w);
        }
        ushort4 u;
        u.x = f2bfu(v.x); u.y = f2bfu(v.y); u.z = f2bfu(v.z); u.w = f2bfu(v.w);
        *(ushort4*)&Lf[0][it][jw] = u;
    }

    // ---- scores row0 (registers) ----
    float sir0[HH], sii0[HH];
    #pragma unroll
    for (int h = 0; h < HH; ++h) {
        sir0[h] = ((const float*)&si_r0)[h] + abr[h];
        sii0[h] = ((const float*)&si_i0)[h] + abi[h];
    }
    float sc0[4][HH];
    float pmax0[HH] = {-INFINITY, -INFINITY, -INFINITY, -INFINITY};
    #pragma unroll
    for (int e = 0; e < 4; ++e) {
        bool msk = am0[e] > 1e-9f;
        const float* sjrp = (const float*)&sjr[e];
        const float* sjip = (const float*)&sji[e];
        #pragma unroll
        for (int h = 0; h < HH; ++h) {
            float sr = sir0[h] + sjrp[h];
            sr = sr >= 0.f ? sr : a_r * sr;
            float sv = sii0[h] + sjip[h];
            sv = sv >= 0.f ? sv : a_i * sv;
            float val;
            if (msk) val = sr*sr + sv*sv;
            else { const float NEG = -1e9f; val = NEG*NEG + NEG*NEG; }
            sc0[e][h] = val;
            pmax0[h] = fmaxf(pmax0[h], val);
        }
    }
    #pragma unroll
    for (int h = 0; h < HH; ++h) {
        #pragma unroll
        for (int off = 32; off > 0; off >>= 1)
            pmax0[h] = fmaxf(pmax0[h], __shfl_xor(pmax0[h], off));
    }
    if (l == 0) { wredm[0][w][0]=pmax0[0]; wredm[0][w][1]=pmax0[1]; wredm[0][w][2]=pmax0[2]; wredm[0][w][3]=pmax0[3]; }
    __syncthreads();                     // S1: Lf0 + wredm0

    // ---- B-fragment prefetch (shared by both rows) ----
    const char* xtR = wsB + XT_BASE + ((size_t)(0*4 + b)*16 + w*8)*2048;
    const char* xtI = wsB + XT_BASE + ((size_t)(4   + b)*16 + w*8)*2048;
    const int jg  = l >> 4;
    const int bofs = (l & 15)*64 + jg*16;

#define LB(s, BR0,BR1,BI0,BI1) do {                                           \
        BR0 = *(const bf16x8*)(xtR + (s)*2048 +        bofs);                 \
        BR1 = *(const bf16x8*)(xtR + (s)*2048 + 1024 + bofs);                 \
        BI0 = *(const bf16x8*)(xtI + (s)*2048 +        bofs);                 \
        BI1 = *(const bf16x8*)(xtI + (s)*2048 + 1024 + bofs);                 \
    } while (0)

    bf16x8 pR0,pR1,pI0,pI1, qR0,qR1,qI0,qI1;
    LB(0, pR0,pR1,pI0,pI1);
    LB(1, qR0,qR1,qI0,qI1);

    // ---- exp row0 ----
    float hm0[HH];
    #pragma unroll
    for (int h = 0; h < HH; ++h) hm0[h] = fmaxf(wredm[0][0][h], wredm[0][1][h]);
    float psum0[HH];
    #pragma unroll
    for (int h = 0; h < HH; ++h) {
        float4 ev;
        ev.x = __expf(sc0[0][h] - hm0[h]);
        ev.y = __expf(sc0[1][h] - hm0[h]);
        ev.z = __expf(sc0[2][h] - hm0[h]);
        ev.w = __expf(sc0[3][h] - hm0[h]);
        *(float4*)&awf[0][h][jw] = ev;
        psum0[h] = (ev.x + ev.y) + (ev.z + ev.w);
        #pragma unroll
        for (int off = 32; off > 0; off >>= 1)
            psum0[h] += __shfl_xor(psum0[h], off);
    }
    if (l == 0) { wreds[0][w][0]=psum0[0]; wreds[0][w][1]=psum0[1]; wreds[0][w][2]=psum0[2]; wreds[0][w][3]=psum0[3]; }

    // ---- stage row1 + mask + scores row1 ----
    float am1[4] = {0.f,0.f,0.f,0.f};
    #pragma unroll
    for (int it = 0; it < 8; ++it) {
        float4 v = v1[it];
        if (it < 4) {
            am1[0] += fabsf(v.x); am1[1] += fabsf(v.y);
            am1[2] += fabsf(v.z); am1[3] += fabsf(v.w);
        }
        ushort4 u;
        u.x = f2bfu(v.x); u.y = f2bfu(v.y); u.z = f2bfu(v.z); u.w = f2bfu(v.w);
        *(ushort4*)&Lf[1][it][jw] = u;
    }
    float sir1[HH], sii1[HH];
    #pragma unroll
    for (int h = 0; h < HH; ++h) {
        sir1[h] = ((const float*)&si_r1)[h] + abr[h];
        sii1[h] = ((const float*)&si_i1)[h] + abi[h];
    }
    float sc1[4][HH];
    float pmax1[HH] = {-INFINITY, -INFINITY, -INFINITY, -INFINITY};
    #pragma unroll
    for (int e = 0; e < 4; ++e) {
        bool msk = am1[e] > 1e-9f;
        const float* sjrp = (const float*)&sjr[e];
        const float* sjip = (const float*)&sji[e];
        #pragma unroll
        for (int h = 0; h < HH; ++h) {
            float sr = sir1[h] + sjrp[h];
            sr = sr >= 0.f ? sr : a_r * sr;
            float sv = sii1[h] + sjip[h];
            sv = sv >= 0.f ? sv : a_i * sv;
            float val;
            if (msk) val = sr*sr + sv*sv;
            else { const float NEG = -1e9f; val = NEG*NEG + NEG*NEG; }
            sc1[e][h] = val;
            pmax1[h] = fmaxf(pmax1[h], val);
        }
    }
    #pragma unroll
    for (int h = 0; h < HH; ++h) {
        #pragma unroll
        for (int off = 32; off > 0; off >>= 1)
            pmax1[h] = fmaxf(pmax1[h], __shfl_xor(pmax1[h], off));
    }
    if (l == 0) { wredm[1][w][0]=pmax1[0]; wredm[1][w][1]=pmax1[1]; wredm[1][w][2]=pmax1[2]; wredm[1][w][3]=pmax1[3]; }
    __syncthreads();                     // S2: awf0 + wreds0 + Lf1 + wredm1

    float inv0[HH];
    #pragma unroll
    for (int h = 0; h < HH; ++h) inv0[h] = 1.0f / (wreds[0][0][h] + wreds[0][1][h]);

    // ---- exp row1 ----
    float hm1[HH];
    #pragma unroll
    for (int h = 0; h < HH; ++h) hm1[h] = fmaxf(wredm[1][0][h], wredm[1][1][h]);
    float psum1[HH];
    #pragma unroll
    for (int h = 0; h < HH; ++h) {
        float4 ev;
        ev.x = __expf(sc1[0][h] - hm1[h]);
        ev.y = __expf(sc1[1][h] - hm1[h]);
        ev.z = __expf(sc1[2][h] - hm1[h]);
        ev.w = __expf(sc1[3][h] - hm1[h]);
        *(float4*)&awf[1][h][jw] = ev;
        psum1[h] = (ev.x + ev.y) + (ev.z + ev.w);
        #pragma unroll
        for (int off = 32; off > 0; off >>= 1)
            psum1[h] += __shfl_xor(psum1[h], off);
    }
    if (l == 0) { wreds[1][w][0]=psum1[0]; wreds[1][w][1]=psum1[1]; wreds[1][w][2]=psum1[2]; wreds[1][w][3]=psum1[3]; }
    __syncthreads();                     // S3: awf1 + wreds1

    float inv1[HH];
    #pragma unroll
    for (int h = 0; h < HH; ++h) inv1[h] = 1.0f / (wreds[1][0][h] + wreds[1][1][h]);

    // ---- JOINT P3: 8 steps, B shared, 16 MFMA/step ----
    const int r_a = l & 15;              // A row = k*4+h
    const int k_a = r_a >> 2, h_a = r_a & 3;

    f32x4 acc0[8], acc1[8];              // RR0 RR1 II0 II1 RI0 RI1 IR0 IR1
    #pragma unroll
    for (int a = 0; a < 8; ++a) { acc0[a] = (f32x4){0.f,0.f,0.f,0.f}; acc1[a] = (f32x4){0.f,0.f,0.f,0.f}; }

#define COMP(s, BR0,BR1,BI0,BI1) do {                                         \
        const int j0_ = w*256 + (s)*32 + jg*8;                                \
        bf16x8 LR0 = *(const bf16x8*)&Lf[0][k_a][j0_];                        \
        bf16x8 LI0 = *(const bf16x8*)&Lf[0][4 + k_a][j0_];                    \
        bf16x8 LR1 = *(const bf16x8*)&Lf[1][k_a][j0_];                        \
        bf16x8 LI1 = *(const bf16x8*)&Lf[1][4 + k_a][j0_];                    \
        float aw0_[8], aw1_[8];                                               \
        *(float4*)&aw0_[0] = *(const float4*)&awf[0][h_a][j0_];               \
        *(float4*)&aw0_[4] = *(const float4*)&awf[0][h_a][j0_ + 4];           \
        *(float4*)&aw1_[0] = *(const float4*)&awf[1][h_a][j0_];               \
        *(float4*)&aw1_[4] = *(const float4*)&awf[1][h_a][j0_ + 4];           \
        bf16x8 Ar0_, Ai0_, Ar1_, Ai1_;                                        \
        _Pragma("unroll")                                                     \
        for (int e_ = 0; e_ < 8; ++e_) {                                      \
            Ar0_[e_] = f2bfs(bfu2f((ushort)LR0[e_]) * aw0_[e_]);              \
            Ai0_[e_] = f2bfs(bfu2f((ushort)LI0[e_]) * aw0_[e_]);              \
            Ar1_[e_] = f2bfs(bfu2f((ushort)LR1[e_]) * aw1_[e_]);              \
            Ai1_[e_] = f2bfs(bfu2f((ushort)LI1[e_]) * aw1_[e_]);              \
        }                                                                     \
        acc0[0] = __builtin_amdgcn_mfma_f32_16x16x32_bf16(Ar0_, BR0, acc0[0],0,0,0); \
        acc0[1] = __builtin_amdgcn_mfma_f32_16x16x32_bf16(Ar0_, BR1, acc0[1],0,0,0); \
        acc0[2] = __builtin_amdgcn_mfma_f32_16x16x32_bf16(Ai0_, BI0, acc0[2],0,0,0); \
        acc0[3] = __builtin_amdgcn_mfma_f32_16x16x32_bf16(Ai0_, BI1, acc0[3],0,0,0); \
        acc0[4] = __builtin_amdgcn_mfma_f32_16x16x32_bf16(Ar0_, BI0, acc0[4],0,0,0); \
        acc0[5] = __builtin_amdgcn_mfma_f32_16x16x32_bf16(Ar0_, BI1, acc0[5],0,0,0); \
        acc0[6] = __builtin_amdgcn_mfma_f32_16x16x32_bf16(Ai0_, BR0, acc0[6],0,0,0); \
        acc0[7] = __builtin_amdgcn_mfma_f32_16x16x32_bf16(Ai0_, BR1, acc0[7],0,0,0); \
        acc1[0] = __builtin_amdgcn_mfma_f32_16x16x32_bf16(Ar1_, BR0, acc1[0],0,0,0); \
        acc1[1] = __builtin_amdgcn_mfma_f32_16x16x32_bf16(Ar1_, BR1, acc1[1],0,0,0); \
        acc1[2] = __builtin_amdgcn_mfma_f32_16x16x32_bf16(Ai1_, BI0, acc1[2],0,0,0); \
        acc1[3] = __builtin_amdgcn_mfma_f32_16x16x32_bf16(Ai1_, BI1, acc1[3],0,0,0); \
        acc1[4] = __builtin_amdgcn_mfma_f32_16x16x32_bf16(Ar1_, BI0, acc1[4],0,0,0); \
        acc1[5] = __builtin_amdgcn_mfma_f32_16x16x32_bf16(Ar1_, BI1, acc1[5],0,0,0); \
        acc1[6] = __builtin_amdgcn_mfma_f32_16x16x32_bf16(Ai1_, BR0, acc1[6],0,0,0); \
        acc1[7] = __builtin_amdgcn_mfma_f32_16x16x32_bf16(Ai1_, BR1, acc1[7],0,0,0); \
    } while (0)

    COMP(0, pR0,pR1,pI0,pI1);
    LB(2, pR0,pR1,pI0,pI1);
    COMP(1, qR0,qR1,qI0,qI1);
    LB(3, qR0,qR1,qI0,qI1);
    COMP(2, pR0,pR1,pI0,pI1);
    LB(4, pR0,pR1,pI0,pI1);
    COMP(3, qR0,qR1,qI0,qI1);
    LB(5, qR0,qR1,qI0,qI1);
    COMP(4, pR0,pR1,pI0,pI1);
    LB(6, pR0,pR1,pI0,pI1);
    COMP(5, qR0,qR1,qI0,qI1);
    LB(7, qR0,qR1,qI0,qI1);
    COMP(6, pR0,pR1,pI0,pI1);
    COMP(7, qR0,qR1,qI0,qI1);
#undef LB
#undef COMP

    __syncthreads();                     // S4: all awf/Lf reads done

    // ---- joint epilogue: both rows, 2 barriers ----
    float* pbuf0 = &awf[0][0][0];        // 2080 floats each
    float* pbuf1 = &awf[1][0][0];
    if (w == 1) {
        #pragma unroll
        for (int ae = 0; ae < 4; ++ae)
            #pragma unroll
            for (int r = 0; r < 4; ++r) {
                pbuf0[(ae*4 + r)*64 + l] = acc0[2*ae][r];
                pbuf1[(ae*4 + r)*64 + l] = acc1[2*ae][r];
            }
    } else {
        #pragma unroll
        for (int ao = 0; ao < 4; ++ao)
            #pragma unroll
            for (int r = 0; r < 4; ++r) {
                pbuf0[1024 + (ao*4 + r)*64 + l] = acc0[2*ao + 1][r];
                pbuf1[1024 + (ao*4 + r)*64 + l] = acc1[2*ao + 1][r];
            }
    }
    __syncthreads();                     // S5

    const int kk = l >> 4, lc = l & 15;
    char* lxp0 = wsB + LX_BASE + (size_t)bn0*2048;
    char* lxp1 = lxp0 + 2048;
    if (w == 0) {
        #pragma unroll
        for (int ae = 0; ae < 4; ++ae)
            #pragma unroll
            for (int r = 0; r < 4; ++r) {
                acc0[2*ae][r] += pbuf0[(ae*4 + r)*64 + l];
                acc1[2*ae][r] += pbuf1[(ae*4 + r)*64 + l];
            }
        #pragma unroll
        for (int r = 0; r < 4; ++r) {    // r == h
            float iv0 = inv0[r], iv1 = inv1[r];
            *(ushort*)(lxp0 + r*512 +       kk*64 + lc*2) = f2bfu((acc0[0][r] - acc0[2][r]) * iv0);
            *(ushort*)(lxp0 + r*512 + 256 + kk*64 + lc*2) = f2bfu((acc0[4][r] + acc0[6][r]) * iv0);
            *(ushort*)(lxp1 + r*512 +       kk*64 + lc*2) = f2bfu((acc1[0][r] - acc1[2][r]) * iv1);
            *(ushort*)(lxp1 + r*512 + 256 + kk*64 + lc*2) = f2bfu((acc1[4][r] + acc1[6][r]) * iv1);
        }
    } else {
        #pragma unroll
        for (int ao = 0; ao < 4; ++ao)
            #pragma unroll
            for (int r = 0; r < 4; ++r) {
                acc0[2*ao + 1][r] += pbuf0[1024 + (ao*4 + r)*64 + l];
                acc1[2*ao + 1][r] += pbuf1[1024 + (ao*4 + r)*64 + l];
            }
        const int c = 16 + lc;
        #pragma unroll
        for (int r = 0; r < 4; ++r) {
            float iv0 = inv0[r], iv1 = inv1[r];
            *(ushort*)(lxp0 + r*512 +       kk*64 + c*2) = f2bfu((acc0[1][r] - acc0[3][r]) * iv0);
            *(ushort*)(lxp0 + r*512 + 256 + kk*64 + c*2) = f2bfu((acc0[5][r] + acc0[7][r]) * iv0);
            *(ushort*)(lxp1 + r*512 +       kk*64 + c*2) = f2bfu((acc1[1][r] - acc1[3][r]) * iv1);
            *(ushort*)(lxp1 + r*512 + 256 + kk*64 + c*2) = f2bfu((acc1[5][r] + acc1[7][r]) * iv1);
        }
    }
}

// ---------------------------------------------------------------------------
// Out GEMM: Y[bn,o] = [LXr|LXi] @ Bre/Bim (K=256), + bias.
// grid 512 blocks (Mtile*4 + Nt) x 256 thr; wave = h.
// ---------------------------------------------------------------------------
__global__ __launch_bounds__(256) void out_gemm_kernel(
    const char* __restrict__ wsB,
    const float* __restrict__ bsr, const float* __restrict__ bsi,
    float* __restrict__ out)
{
    const int Mtile = blockIdx.x >> 2;
    const int Nt    = blockIdx.x & 3;
    const int t = threadIdx.x, l = t & 63, h = t >> 6;

    const char* abase = wsB + LX_BASE + ((size_t)(Mtile*16 + (l & 15)))*2048
                        + h*512 + (l >> 4)*16;
    f32x4 are = (f32x4){0.f,0.f,0.f,0.f};
    f32x4 aim = (f32x4){0.f,0.f,0.f,0.f};
    const size_t fbase = ((size_t)((h*4 + Nt)*8))*1024 + (size_t)l*16;
    const char* bre = wsB + BRE_BASE + fbase;
    const char* bim = wsB + BIM_BASE + fbase;
    #pragma unroll
    for (int s = 0; s < 8; ++s) {
        bf16x8 Af = *(const bf16x8*)(abase + s*64);
        bf16x8 Br = *(const bf16x8*)(bre + s*1024);
        bf16x8 Bi = *(const bf16x8*)(bim + s*1024);
        are = __builtin_amdgcn_mfma_f32_16x16x32_bf16(Af, Br, are, 0, 0, 0);
        aim = __builtin_amdgcn_mfma_f32_16x16x32_bf16(Af, Bi, aim, 0, 0, 0);
    }
    const int p = Nt*16 + (l & 15), o = p*4 + h;
    const float vbr = bsr[o], vbi = bsi[o];
    #pragma unroll
    for (int r = 0; r < 4; ++r) {
        int bn = Mtile*16 + (l >> 4)*4 + r;
        out[(size_t)bn*AOUT + o] = are[r] + vbr;
        out[(size_t)BB*NN*AOUT + (size_t)bn*AOUT + o] = aim[r] + vbi;
    }
}

// ---------------------------------------------------------------------------
extern "C" void kernel_launch(void* const* d_in, const int* in_sizes, int n_in,
                              void* d_out, int out_size, void* d_ws, size_t ws_size,
                              hipStream_t stream)
{
    const float* Xr  = (const float*)d_in[0];
    const float* Xi  = (const float*)d_in[1];
    const float* Lr  = (const float*)d_in[2];
    const float* Li  = (const float*)d_in[3];
    const float* Wr  = (const float*)d_in[4];
    const float* Wi  = (const float*)d_in[5];
    const float* AWr = (const float*)d_in[6];
    const float* AWi = (const float*)d_in[7];
    const float* abr = (const float*)d_in[8];
    const float* abi = (const float*)d_in[9];
    const float* par = (const float*)d_in[10];
    const float* pai = (const float*)d_in[11];
    const float* bsr = (const float*)d_in[12];
    const float* bsi = (const float*)d_in[13];
    float* ws  = (float*)d_ws;
    char*  wsB = (char*)d_ws;
    float* out = (float*)d_out;

    hipLaunchKernelGGL(prep_kernel, dim3(96), dim3(256), 0, stream,
                       Xr, Xi, AWr, AWi, Wr, Wi, ws, wsB);
    hipLaunchKernelGGL(cheb_main_kernel, dim3(BB*NN/2), dim3(128), 0, stream,
                       Lr, Li, abr, abi, par, pai, ws, wsB);
    hipLaunchKernelGGL(out_gemm_kernel, dim3(512), dim3(256), 0, stream,
                       wsB, bsr, bsi, out);
}